// Round 2
// baseline (312.297 us; speedup 1.0000x reference)
//
#include <hip/hip_runtime.h>
#include <hip/hip_fp16.h>

// Problem constants (from reference)
#define N0C 4096
#define E0C 16384
#define N1C 1024
#define E1C 8192
#define HC 64          // hidden / channels
#define FINC 8
#define LATC 32
#define FC 67          // H + DIM
#define E0T (E0C + N0C)   // edges incl. self loops, level 0
#define E1T (E1C + N1C)   // level 1

typedef float f32x4 __attribute__((ext_vector_type(4)));
typedef _Float16 f16x8 __attribute__((ext_vector_type(8)));

// ---------------- encoder: h0 = sin(0.01*(x@lin0_w + lin0_b)) ----------------
__global__ void k_encoder(const float* __restrict__ x, const float* __restrict__ w,
                          const float* __restrict__ b, float* __restrict__ h0) {
  int id = blockIdx.x * blockDim.x + threadIdx.x;
  if (id >= N0C * HC) return;
  int n = id >> 6, j = id & 63;
  float a = b[j];
#pragma unroll
  for (int f = 0; f < FINC; ++f) a = fmaf(x[n * FINC + f], w[f * HC + j], a);
  h0[id] = sinf(0.01f * a);
}

// ------ channel basis for BOTH levels: cB/sB[c,h] = cos/sin(0.1*c*w0[3,h]) ---
__global__ void k_chanprep2(const float* __restrict__ w00, const float* __restrict__ w01,
                            float* __restrict__ cB0, float* __restrict__ sB0,
                            float* __restrict__ cB1, float* __restrict__ sB1) {
  int id = blockIdx.x * blockDim.x + threadIdx.x;  // 2*64*64
  int lvl = id >= HC * HC;
  int id2 = id & (HC * HC - 1);
  int c = id2 >> 6, hh = id2 & 63;
  const float* w = lvl ? w01 : w00;
  float arg = 0.1f * (float)c * w[3 * HC + hh];
  float s, cv;
  sincosf(arg, &s, &cv);
  (lvl ? sB1 : sB0)[id2] = s;
  (lvl ? cB1 : cB0)[id2] = cv;
}

// ---------------- CSR build: degree count (both levels, int atomics) ---------
__global__ void k_degree(const int* __restrict__ ei0, const int* __restrict__ ei1,
                         int* __restrict__ cnt) {
  int id = blockIdx.x * blockDim.x + threadIdx.x;  // E0T + E1T
  if (id < E0T) {
    int e = id;
    int dst = (e < E0C) ? ei0[E0C + e] : (e - E0C);
    atomicAdd(cnt + dst, 1);
  } else {
    int e = id - E0T;
    int dst = (e < E1C) ? ei1[E1C + e] : (e - E1C);
    atomicAdd(cnt + N0C + dst, 1);
  }
}

// ---------------- CSR build: exclusive scan (block 0: L0, block 1: L1) -------
__global__ void k_scan(const int* __restrict__ cnt, int* __restrict__ rp0,
                       int* __restrict__ rp1) {
  __shared__ int s[1024];
  const int b = blockIdx.x;
  const int n = b ? N1C : N0C;
  const int* c = cnt + (b ? N0C : 0);
  int* rp = b ? rp1 : rp0;
  const int tid = threadIdx.x;
  const int per = n >> 10;  // 4 or 1
  int loc[4];
  int sum = 0;
  for (int j = 0; j < per; ++j) { loc[j] = c[tid * per + j]; sum += loc[j]; }
  s[tid] = sum;
  __syncthreads();
  for (int off = 1; off < 1024; off <<= 1) {
    int v = s[tid] + ((tid >= off) ? s[tid - off] : 0);
    __syncthreads();
    s[tid] = v;
    __syncthreads();
  }
  int base = tid ? s[tid - 1] : 0;
  for (int j = 0; j < per; ++j) { rp[tid * per + j] = base; base += loc[j]; }
  if (tid == 1023) rp[n] = s[1023];
}

// ---------------- CSR build: scatter edge ids ---------------------------------
__global__ void k_scatter(const int* __restrict__ ei0, const int* __restrict__ ei1,
                          const int* __restrict__ rp0, const int* __restrict__ rp1,
                          int* __restrict__ fill, int* __restrict__ eidx0,
                          int* __restrict__ eidx1) {
  int id = blockIdx.x * blockDim.x + threadIdx.x;
  if (id < E0T) {
    int e = id;
    int dst = (e < E0C) ? ei0[E0C + e] : (e - E0C);
    int p = rp0[dst] + atomicAdd(fill + dst, 1);
    eidx0[p] = e;
  } else {
    int e = id - E0T;
    int dst = (e < E1C) ? ei1[E1C + e] : (e - E1C);
    int p = rp1[dst] + atomicAdd(fill + N0C + dst, 1);
    eidx1[p] = e;
  }
}

// ---------------- conv core (fused edge-prep + 64x64x64 MFMA + epilogue) -----
// Per wave, per edge e:
//   feats -> base[h] -> (sv,cv); A[c,h]=sv[h]*cB[c,h]+cv[h]*sB[c,h] built as
//   fp16 A-fragments IN REGISTERS (A-frag layout: lane holds A[m=lane&15][k=q*8+j]);
//   z = A@w1 via mfma_f32_16x16x32_f16; msg[e,c] = sum_k sin(0.1z+0.1b1[k])*t[e,k] + d[e]
//   written as plain float4 stores (NO atomics).
__global__ __launch_bounds__(256) void k_conv(
    const int* __restrict__ ei, int E, int eTot,
    const float* __restrict__ posp, const float* __restrict__ hbuf,
    const float* __restrict__ kw0, const float* __restrict__ kb0,
    const float* __restrict__ kw2, const float* __restrict__ kb2,
    const float* __restrict__ cB, const float* __restrict__ sB,
    const float* __restrict__ w1, const float* __restrict__ b1,
    float* __restrict__ msg) {
  __shared__ __attribute__((aligned(16))) _Float16 Bt[64][72];  // Bt[n][k]=w1[k,n]
  __shared__ __attribute__((aligned(16))) float scS[4][64];     // per-wave sv[h]
  __shared__ __attribute__((aligned(16))) float scC[4][64];     // per-wave cv[h]
  const int tid = threadIdx.x;
  const int wave = tid >> 6, lane = tid & 63;
  const int m_row = lane & 15, q = lane >> 4;

  for (int idx = tid; idx < HC * HC; idx += 256) {
    int nn = idx & 63, k = idx >> 6;
    Bt[nn][k] = (_Float16)w1[k * HC + nn];  // w1[tid] coalesced
  }
  float b1s[4];
#pragma unroll
  for (int nt = 0; nt < 4; ++nt) b1s[nt] = 0.1f * b1[nt * 16 + m_row];
  __syncthreads();  // Bt ready

  const int nW = gridDim.x * 4;
  for (int e = blockIdx.x * 4 + wave; e < eTot; e += nW) {
    int s, d2;
    if (e < E) { s = ei[e]; d2 = ei[E + e]; } else { s = e - E; d2 = s; }
    const float px = posp[s * 3 + 0], py = posp[s * 3 + 1], pz = posp[s * 3 + 2];
    const float rx = posp[d2 * 3 + 0] - px;
    const float ry = posp[d2 * 3 + 1] - py;
    const float rz = posp[d2 * 3 + 2] - pz;
    float f0 = 0.f, f1 = 0.f, f2 = 0.f;
    if (!(rx == 0.f && ry == 0.f && rz == 0.f)) {
      const float PI_F = 3.14159265358979323846f;
      float rho = sqrtf(rx * rx + ry * ry + rz * rz);
      float th = atan2f(ry, rx);
      float ratio = fminf(1.f, fmaxf(-1.f, rz / rho));
      float ph = asinf(ratio);
      f0 = rho; f1 = th / PI_F; f2 = ph / PI_F;
    }
    float base = kb0[lane];
    base = fmaf(f0, kw0[0 * HC + lane], base);
    base = fmaf(f1, kw0[1 * HC + lane], base);
    base = fmaf(f2, kw0[2 * HC + lane], base);
    float sv, cv;
    sincosf(0.1f * base, &sv, &cv);
    scS[wave][lane] = sv;
    scC[wave][lane] = cv;

    // t[k=lane] = w2[k,:] . xj ;  d = xj . b2  (xj = [hbuf[s] || pos[s]])
    const float* xrow = hbuf + (size_t)s * HC;  // wave-uniform -> scalar loads
    const float* wrow = kw2 + lane * FC;
    float tl = 0.f;
#pragma unroll 8
    for (int f = 0; f < HC; ++f) tl = fmaf(wrow[f], xrow[f], tl);
    tl = fmaf(wrow[64], px, fmaf(wrow[65], py, fmaf(wrow[66], pz, tl)));
    float pd = xrow[lane] * kb2[lane];
    if (lane == 0) pd = fmaf(px, kb2[64], pd);
    if (lane == 1) pd = fmaf(py, kb2[65], pd);
    if (lane == 2) pd = fmaf(pz, kb2[66], pd);
#pragma unroll
    for (int m2 = 1; m2 < 64; m2 <<= 1) pd += __shfl_xor(pd, m2, 64);

    // A-frags in registers + MFMA
    f32x4 acc[4][4];
    const f32x4 zero = {0.f, 0.f, 0.f, 0.f};
#pragma unroll
    for (int ms = 0; ms < 4; ++ms)
#pragma unroll
      for (int nt = 0; nt < 4; ++nt) acc[ms][nt] = zero;

#pragma unroll
    for (int ks = 0; ks < 2; ++ks) {
      const int h0i = ks * 32 + q * 8;  // k-range of this frag
      f32x4 sv0 = *(const f32x4*)&scS[wave][h0i];
      f32x4 sv1 = *(const f32x4*)&scS[wave][h0i + 4];
      f32x4 cv0 = *(const f32x4*)&scC[wave][h0i];
      f32x4 cv1 = *(const f32x4*)&scC[wave][h0i + 4];
      f16x8 bf[4];
#pragma unroll
      for (int nt = 0; nt < 4; ++nt)
        bf[nt] = *(const f16x8*)(&Bt[nt * 16 + m_row][h0i]);
#pragma unroll
      for (int ms = 0; ms < 4; ++ms) {
        const int c = ms * 16 + m_row;
        const float* cbp = cB + c * HC + h0i;
        const float* sbp = sB + c * HC + h0i;
        f32x4 cb0 = *(const f32x4*)cbp, cb1 = *(const f32x4*)(cbp + 4);
        f32x4 sb0 = *(const f32x4*)sbp, sb1 = *(const f32x4*)(sbp + 4);
        f16x8 af;
#pragma unroll
        for (int j = 0; j < 4; ++j) {
          af[j]     = (_Float16)fmaf(sv0[j], cb0[j], cv0[j] * sb0[j]);
          af[4 + j] = (_Float16)fmaf(sv1[j], cb1[j], cv1[j] * sb1[j]);
        }
#pragma unroll
        for (int nt = 0; nt < 4; ++nt)
          acc[ms][nt] = __builtin_amdgcn_mfma_f32_16x16x32_f16(af, bf[nt], acc[ms][nt], 0, 0, 0);
      }
    }

    // epilogue: D[row=c=(ms*16+q*4+r)][col=k=(nt*16+m_row)]
    float tr[4];
#pragma unroll
    for (int nt = 0; nt < 4; ++nt) tr[nt] = __shfl(tl, nt * 16 + m_row, 64);
    float* orow = msg + (size_t)e * HC;
#pragma unroll
    for (int ms = 0; ms < 4; ++ms) {
      float p0 = 0.f, p1 = 0.f, p2 = 0.f, p3 = 0.f;
#pragma unroll
      for (int nt = 0; nt < 4; ++nt) {
        f32x4 z = acc[ms][nt];
        p0 = fmaf(__sinf(fmaf(0.1f, z[0], b1s[nt])), tr[nt], p0);
        p1 = fmaf(__sinf(fmaf(0.1f, z[1], b1s[nt])), tr[nt], p1);
        p2 = fmaf(__sinf(fmaf(0.1f, z[2], b1s[nt])), tr[nt], p2);
        p3 = fmaf(__sinf(fmaf(0.1f, z[3], b1s[nt])), tr[nt], p3);
      }
#pragma unroll
      for (int m2 = 1; m2 < 16; m2 <<= 1) {
        p0 += __shfl_xor(p0, m2, 64);
        p1 += __shfl_xor(p1, m2, 64);
        p2 += __shfl_xor(p2, m2, 64);
        p3 += __shfl_xor(p3, m2, 64);
      }
      if (m_row == 0) {
        f32x4 v = {p0 + pd, p1 + pd, p2 + pd, p3 + pd};
        *(f32x4*)(orow + ms * 16 + q * 4) = v;
      }
    }
  }
}

// ---- CSR segment-sum of msg rows + fused sin(0.01*(sum+bias)) ---------------
__global__ void k_reduce(const float* __restrict__ msg, const int* __restrict__ eidx,
                         const int* __restrict__ rp, const float* __restrict__ bias,
                         float* __restrict__ outp, int n) {
  int wave = threadIdx.x >> 6, lane = threadIdx.x & 63;
  int node = blockIdx.x * 4 + wave;
  if (node >= n) return;
  int j0 = rp[node], j1 = rp[node + 1];
  float s = 0.f;
  for (int j = j0; j < j1; ++j) s += msg[(size_t)eidx[j] * HC + lane];
  outp[node * HC + lane] = sinf(0.01f * (s + bias[lane]));
}

// ---- pool: max over incident edges' src (CSR), only for kept nodes ----------
__global__ void k_pool(const float* __restrict__ hc, const int* __restrict__ eidx,
                       const int* __restrict__ rp, const int* __restrict__ ei,
                       const int* __restrict__ keep, float* __restrict__ h1in) {
  int wave = threadIdx.x >> 6, lane = threadIdx.x & 63;
  int i = blockIdx.x * 4 + wave;
  if (i >= N1C) return;
  int n = keep[i];
  int j0 = rp[n], j1 = rp[n + 1];
  float m = -INFINITY;
  for (int j = j0; j < j1; ++j) {
    int e = eidx[j];
    int src = (e < E0C) ? ei[e] : (e - E0C);
    m = fmaxf(m, hc[(size_t)src * HC + lane]);
  }
  h1in[i * HC + lane] = m;
}

// ---------------- final: out = sin(0.01*(hc1@lin1_w + lin1_b)) ---------------
__global__ void k_final(const float* __restrict__ hc1, const float* __restrict__ w,
                        const float* __restrict__ b, float* __restrict__ outp) {
  int id = blockIdx.x * blockDim.x + threadIdx.x;  // N1*LAT
  if (id >= N1C * LATC) return;
  int i = id >> 5, l = id & 31;
  float a = b[l];
#pragma unroll 8
  for (int c = 0; c < HC; ++c) a = fmaf(hc1[i * HC + c], w[c * LATC + l], a);
  outp[id] = sinf(0.01f * a);
}

extern "C" void kernel_launch(void* const* d_in, const int* in_sizes, int n_in,
                              void* d_out, int out_size, void* d_ws, size_t ws_size,
                              hipStream_t stream) {
  (void)in_sizes; (void)n_in; (void)out_size; (void)ws_size;
  const float* x    = (const float*)d_in[0];
  const float* pos  = (const float*)d_in[1];
  const int*   ei   = (const int*)d_in[2];
  const int*   pei  = (const int*)d_in[3];
  const float* ppos = (const float*)d_in[4];
  const int*   keep = (const int*)d_in[5];
  const float* l0w  = (const float*)d_in[6];
  const float* l0b  = (const float*)d_in[7];
  const float* l1w  = (const float*)d_in[8];
  const float* l1b  = (const float*)d_in[9];
  const float* c0w0 = (const float*)d_in[10];
  const float* c0b0 = (const float*)d_in[11];
  const float* c0w1 = (const float*)d_in[12];
  const float* c0b1 = (const float*)d_in[13];
  const float* c0w2 = (const float*)d_in[14];
  const float* c0b2 = (const float*)d_in[15];
  const float* c0bias = (const float*)d_in[16];
  const float* c1w0 = (const float*)d_in[17];
  const float* c1b0 = (const float*)d_in[18];
  const float* c1w1 = (const float*)d_in[19];
  const float* c1b1 = (const float*)d_in[20];
  const float* c1w2 = (const float*)d_in[21];
  const float* c1b2 = (const float*)d_in[22];
  const float* c1bias = (const float*)d_in[23];
  float* outp = (float*)d_out;

  char* p = (char*)d_ws;
  auto carve = [&](size_t bytes) -> char* {
    char* r = p;
    p += (bytes + 255) & ~(size_t)255;
    return r;
  };
  float* h0   = (float*)carve((size_t)N0C * HC * 4);
  float* hc0  = (float*)carve((size_t)N0C * HC * 4);
  float* h1in = (float*)carve((size_t)N1C * HC * 4);
  float* hc1  = (float*)carve((size_t)N1C * HC * 4);
  float* cB0 = (float*)carve((size_t)HC * HC * 4);
  float* sB0 = (float*)carve((size_t)HC * HC * 4);
  float* cB1 = (float*)carve((size_t)HC * HC * 4);
  float* sB1 = (float*)carve((size_t)HC * HC * 4);
  // cnt & fill contiguous -> single memset
  int* cnt  = (int*)carve((size_t)(N0C + N1C) * 4);
  int* fill = (int*)carve((size_t)(N0C + N1C) * 4);
  int* rp0 = (int*)carve((size_t)(N0C + 1) * 4);
  int* rp1 = (int*)carve((size_t)(N1C + 1) * 4);
  int* eidx0 = (int*)carve((size_t)E0T * 4);
  int* eidx1 = (int*)carve((size_t)E1T * 4);
  float* msg = (float*)carve((size_t)E0T * HC * 4);  // reused for level 1

  hipMemsetAsync(cnt, 0, (size_t)(N0C + N1C) * 4 * 2, stream);  // cnt + fill

  k_encoder<<<(N0C * HC) / 256, 256, 0, stream>>>(x, l0w, l0b, h0);
  k_chanprep2<<<(2 * HC * HC) / 256, 256, 0, stream>>>(c0w0, c1w0, cB0, sB0, cB1, sB1);
  k_degree<<<(E0T + E1T) / 256, 256, 0, stream>>>(ei, pei, cnt);
  k_scan<<<2, 1024, 0, stream>>>(cnt, rp0, rp1);
  k_scatter<<<(E0T + E1T) / 256, 256, 0, stream>>>(ei, pei, rp0, rp1, fill, eidx0, eidx1);

  k_conv<<<768, 256, 0, stream>>>(ei, E0C, E0T, pos, h0, c0w0, c0b0, c0w2, c0b2,
                                  cB0, sB0, c0w1, c0b1, msg);
  k_reduce<<<N0C / 4, 256, 0, stream>>>(msg, eidx0, rp0, c0bias, hc0, N0C);
  k_pool<<<N1C / 4, 256, 0, stream>>>(hc0, eidx0, rp0, ei, keep, h1in);

  k_conv<<<768, 256, 0, stream>>>(pei, E1C, E1T, ppos, h1in, c1w0, c1b0, c1w2, c1b2,
                                  cB1, sB1, c1w1, c1b1, msg);
  k_reduce<<<N1C / 4, 256, 0, stream>>>(msg, eidx1, rp1, c1bias, hc1, N1C);
  k_final<<<(N1C * LATC) / 256, 256, 0, stream>>>(hc1, l1w, l1b, outp);
}

// Round 3
// 194.427 us; speedup vs baseline: 1.6062x; 1.6062x over previous
//
#include <hip/hip_runtime.h>
#include <hip/hip_fp16.h>

// Problem constants (from reference)
#define N0C 4096
#define E0C 16384
#define N1C 1024
#define E1C 8192
#define HC 64
#define FINC 8
#define LATC 32
#define FC 67
#define E0T (E0C + N0C)
#define E1T (E1C + N1C)

typedef float f32x4 __attribute__((ext_vector_type(4)));
typedef _Float16 f16x8 __attribute__((ext_vector_type(8)));

// ---- k_misc: pack basis/w1 fragments (fp16), transpose w2, degree count ----
// ranges: [0,8192) basis both levels; [8192,16384) w1f; [16384,24960) w2t;
//         [24960,54656) degree
__global__ void k_misc(const float* __restrict__ c0w0, const float* __restrict__ c1w0,
                       const float* __restrict__ c0w1, const float* __restrict__ c1w1,
                       const float* __restrict__ c0w2, const float* __restrict__ c1w2,
                       const int* __restrict__ ei0, const int* __restrict__ ei1,
                       _Float16* __restrict__ bC0, _Float16* __restrict__ bS0,
                       _Float16* __restrict__ bC1, _Float16* __restrict__ bS1,
                       _Float16* __restrict__ w1f0, _Float16* __restrict__ w1f1,
                       float* __restrict__ w2t0, float* __restrict__ w2t1,
                       int* __restrict__ cnt) {
  int id = blockIdx.x * blockDim.x + threadIdx.x;
  if (id < 8192) {  // basis: bC/bS[((ks*4+nt)*64+lane)*8+j] = cos/sin(0.1*c*w0[3,h])
    int lvl = id >> 12, r = id & 4095;
    int fi = r >> 9, lane = (r >> 3) & 63, j = r & 7;
    int nt = fi & 3, ks = fi >> 2;
    int c = nt * 16 + (lane & 15);
    int h = ks * 32 + (lane >> 4) * 8 + j;
    const float* w = lvl ? c1w0 : c0w0;
    float s, cv;
    sincosf(0.1f * (float)c * w[3 * HC + h], &s, &cv);
    (lvl ? bC1 : bC0)[r] = (_Float16)cv;
    (lvl ? bS1 : bS0)[r] = (_Float16)s;
  } else if (id < 16384) {  // w1f[((ks*4+ms)*64+lane)*8+j] = w1[h, kout]
    int r0 = id - 8192;
    int lvl = r0 >> 12, r = r0 & 4095;
    int fi = r >> 9, lane = (r >> 3) & 63, j = r & 7;
    int ms = fi & 3, ks = fi >> 2;
    int h = ks * 32 + (lane >> 4) * 8 + j;
    int kout = ms * 16 + (lane & 15);
    const float* w = lvl ? c1w1 : c0w1;
    (lvl ? w1f1 : w1f0)[r] = (_Float16)w[h * HC + kout];
  } else if (id < 24960) {  // w2t[f*64+k] = w2[k*67+f]
    int r = id - 16384;
    int lvl = r >= FC * HC;
    r -= lvl * FC * HC;
    int f = r >> 6, k = r & 63;
    (lvl ? w2t1 : w2t0)[r] = (lvl ? c1w2 : c0w2)[k * FC + f];
  } else if (id < 54656) {  // degree
    int r = id - 24960;
    if (r < E0T) {
      int dst = (r < E0C) ? ei0[E0C + r] : (r - E0C);
      atomicAdd(cnt + dst, 1);
    } else {
      int e = r - E0T;
      int dst = (e < E1C) ? ei1[E1C + e] : (e - E1C);
      atomicAdd(cnt + N0C + dst, 1);
    }
  }
}

// ---- CSR scan (block 0: level0, block 1: level1) ----------------------------
__global__ void k_scan(const int* __restrict__ cnt, int* __restrict__ rp0,
                       int* __restrict__ rp1) {
  __shared__ int s[1024];
  const int b = blockIdx.x;
  const int n = b ? N1C : N0C;
  const int* c = cnt + (b ? N0C : 0);
  int* rp = b ? rp1 : rp0;
  const int tid = threadIdx.x;
  const int per = n >> 10;
  int loc[4];
  int sum = 0;
  for (int j = 0; j < per; ++j) { loc[j] = c[tid * per + j]; sum += loc[j]; }
  s[tid] = sum;
  __syncthreads();
  for (int off = 1; off < 1024; off <<= 1) {
    int v = s[tid] + ((tid >= off) ? s[tid - off] : 0);
    __syncthreads();
    s[tid] = v;
    __syncthreads();
  }
  int base = tid ? s[tid - 1] : 0;
  for (int j = 0; j < per; ++j) { rp[tid * per + j] = base; base += loc[j]; }
  if (tid == 1023) rp[n] = s[1023];
}

// ---- CSR scatter -------------------------------------------------------------
__global__ void k_scatter(const int* __restrict__ ei0, const int* __restrict__ ei1,
                          const int* __restrict__ rp0, const int* __restrict__ rp1,
                          int* __restrict__ fill, int* __restrict__ eidx0,
                          int* __restrict__ eidx1) {
  int id = blockIdx.x * blockDim.x + threadIdx.x;
  if (id < E0T) {
    int dst = (id < E0C) ? ei0[E0C + id] : (id - E0C);
    eidx0[rp0[dst] + atomicAdd(fill + dst, 1)] = id;
  } else if (id < E0T + E1T) {
    int e = id - E0T;
    int dst = (e < E1C) ? ei1[E1C + e] : (e - E1C);
    eidx1[rp1[dst] + atomicAdd(fill + N0C + dst, 1)] = e;
  }
}

// ---- k_node0: encoder + per-node t/d for level 0 (one wave per node) --------
__global__ void k_node0(const float* __restrict__ x, const float* __restrict__ l0w,
                        const float* __restrict__ l0b, const float* __restrict__ posp,
                        const float* __restrict__ w2t, const float* __restrict__ b2,
                        float* __restrict__ tN, float* __restrict__ dN) {
  __shared__ float xr[4][64];
  const int wave = threadIdx.x >> 6, lane = threadIdx.x & 63;
  const int n = blockIdx.x * 4 + wave;  // grid exact: n < N0C
  float a = l0b[lane];
#pragma unroll
  for (int f = 0; f < FINC; ++f) a = fmaf(x[n * FINC + f], l0w[f * HC + lane], a);
  xr[wave][lane] = sinf(0.01f * a);
  __syncthreads();
  const float px = posp[n * 3], py = posp[n * 3 + 1], pz = posp[n * 3 + 2];
  float tl = 0.f, ds = 0.f;
#pragma unroll 8
  for (int f = 0; f < HC; ++f) {
    float xv = xr[wave][f];
    tl = fmaf(xv, w2t[f * HC + lane], tl);
    ds = fmaf(xv, b2[f], ds);
  }
  tl = fmaf(px, w2t[64 * HC + lane], fmaf(py, w2t[65 * HC + lane], fmaf(pz, w2t[66 * HC + lane], tl)));
  ds = fmaf(px, b2[64], fmaf(py, b2[65], fmaf(pz, b2[66], ds)));
  tN[n * HC + lane] = tl;
  if (lane == 0) dN[n] = ds;
}

// ---- k_conv: fused edge kernel, operand-swapped MFMA, register-resident -----
// D[kout][c]: A_op = w1^T frags (regs), B_op[h][c] = sv[h]*cB[c,h]+cv[h]*sB[c,h]
// built with packed fp16 from register basis frags + LDS-broadcast sv/cv.
__global__ __launch_bounds__(256, 2) void k_conv(
    const int* __restrict__ ei, int E, int eTot,
    const float* __restrict__ posp,
    const float* __restrict__ tN, const float* __restrict__ dN,
    const float* __restrict__ kw0, const float* __restrict__ kb0,
    const _Float16* __restrict__ bC, const _Float16* __restrict__ bS,
    const _Float16* __restrict__ w1f, const float* __restrict__ b1,
    float* __restrict__ msg) {
  __shared__ _Float16 scS[4][64], scC[4][64];
  const int tid = threadIdx.x;
  const int wave = tid >> 6, lane = tid & 63;
  const int q = lane >> 4;

  f16x8 w1r[8], cbr[8], sbr[8];
#pragma unroll
  for (int f = 0; f < 8; ++f) {
    w1r[f] = *(const f16x8*)(w1f + ((f << 6) + lane) * 8);
    cbr[f] = *(const f16x8*)(bC + ((f << 6) + lane) * 8);
    sbr[f] = *(const f16x8*)(bS + ((f << 6) + lane) * 8);
  }
  const float kb0v = kb0[lane];
  const float kw0x = kw0[lane], kw0y = kw0[HC + lane], kw0z = kw0[2 * HC + lane];

  const int nW = gridDim.x * 4;
  for (int e = blockIdx.x * 4 + wave; e < eTot; e += nW) {
    int s, d2;
    if (e < E) { s = ei[e]; d2 = ei[E + e]; } else { s = e - E; d2 = s; }
    const float px = posp[s * 3], py = posp[s * 3 + 1], pz = posp[s * 3 + 2];
    const float rx = posp[d2 * 3] - px;
    const float ry = posp[d2 * 3 + 1] - py;
    const float rz = posp[d2 * 3 + 2] - pz;
    float f0 = 0.f, f1 = 0.f, f2 = 0.f;
    if (!(rx == 0.f && ry == 0.f && rz == 0.f)) {
      const float PI_F = 3.14159265358979323846f;
      float rho = sqrtf(rx * rx + ry * ry + rz * rz);
      float th = atan2f(ry, rx);
      float ratio = fminf(1.f, fmaxf(-1.f, rz / rho));
      float ph = asinf(ratio);
      f0 = rho; f1 = th / PI_F; f2 = ph / PI_F;
    }
    float base = fmaf(f0, kw0x, fmaf(f1, kw0y, fmaf(f2, kw0z, kb0v)));
    float sv, cv;
    sincosf(0.1f * base, &sv, &cv);
    scS[wave][lane] = (_Float16)sv;
    scC[wave][lane] = (_Float16)cv;
    __builtin_amdgcn_wave_barrier();

    f16x8 bf[2][4];
#pragma unroll
    for (int ks = 0; ks < 2; ++ks) {
      f16x8 sv8 = *(const f16x8*)&scS[wave][ks * 32 + q * 8];
      f16x8 cv8 = *(const f16x8*)&scC[wave][ks * 32 + q * 8];
#pragma unroll
      for (int nt = 0; nt < 4; ++nt)
        bf[ks][nt] = sv8 * cbr[ks * 4 + nt] + cv8 * sbr[ks * 4 + nt];
    }

    f32x4 acc[4][4];
    const f32x4 zero = {0.f, 0.f, 0.f, 0.f};
#pragma unroll
    for (int ms = 0; ms < 4; ++ms)
#pragma unroll
      for (int nt = 0; nt < 4; ++nt) acc[ms][nt] = zero;
#pragma unroll
    for (int ks = 0; ks < 2; ++ks)
#pragma unroll
      for (int ms = 0; ms < 4; ++ms)
#pragma unroll
        for (int nt = 0; nt < 4; ++nt)
          acc[ms][nt] = __builtin_amdgcn_mfma_f32_16x16x32_f16(
              w1r[ks * 4 + ms], bf[ks][nt], acc[ms][nt], 0, 0, 0);

    // epilogue: lane(q,m) reg r of acc[ms][nt] = z[kout=ms*16+q*4+r][c=nt*16+m]
    const float dv = dN[s];
    float snt0 = 0.f, snt1 = 0.f, snt2 = 0.f, snt3 = 0.f;
#pragma unroll
    for (int ms = 0; ms < 4; ++ms) {
      f32x4 tv = *(const f32x4*)(tN + (size_t)s * HC + ms * 16 + q * 4);
      f32x4 bv = *(const f32x4*)(b1 + ms * 16 + q * 4);
#pragma unroll
      for (int r = 0; r < 4; ++r) {
        float bb = 0.1f * bv[r], tt = tv[r];
        snt0 = fmaf(__sinf(fmaf(0.1f, acc[ms][0][r], bb)), tt, snt0);
        snt1 = fmaf(__sinf(fmaf(0.1f, acc[ms][1][r], bb)), tt, snt1);
        snt2 = fmaf(__sinf(fmaf(0.1f, acc[ms][2][r], bb)), tt, snt2);
        snt3 = fmaf(__sinf(fmaf(0.1f, acc[ms][3][r], bb)), tt, snt3);
      }
    }
    snt0 += __shfl_xor(snt0, 16, 64); snt0 += __shfl_xor(snt0, 32, 64);
    snt1 += __shfl_xor(snt1, 16, 64); snt1 += __shfl_xor(snt1, 32, 64);
    snt2 += __shfl_xor(snt2, 16, 64); snt2 += __shfl_xor(snt2, 32, 64);
    snt3 += __shfl_xor(snt3, 16, 64); snt3 += __shfl_xor(snt3, 32, 64);
    float val = (q == 0) ? snt0 : (q == 1) ? snt1 : (q == 2) ? snt2 : snt3;
    msg[(size_t)e * HC + lane] = val + dv;  // c == lane: coalesced
  }
}

// ---- CSR segment-sum + sin(0.01*(sum+bias)) ---------------------------------
__global__ void k_reduce(const float* __restrict__ msg, const int* __restrict__ eidx,
                         const int* __restrict__ rp, const float* __restrict__ bias,
                         float* __restrict__ outp, int n) {
  int wave = threadIdx.x >> 6, lane = threadIdx.x & 63;
  int node = blockIdx.x * 4 + wave;
  if (node >= n) return;
  int j0 = rp[node], j1 = rp[node + 1];
  float s = 0.f;
  for (int j = j0; j < j1; ++j) s += msg[(size_t)eidx[j] * HC + lane];
  outp[node * HC + lane] = sinf(0.01f * (s + bias[lane]));
}

// ---- pool (CSR max over kept nodes) + per-node t/d for level 1 --------------
__global__ void k_pool1(const float* __restrict__ hc0, const int* __restrict__ eidx,
                        const int* __restrict__ rp, const int* __restrict__ ei,
                        const int* __restrict__ keep, const float* __restrict__ ppos,
                        const float* __restrict__ w2t, const float* __restrict__ b2,
                        float* __restrict__ tN, float* __restrict__ dN) {
  __shared__ float xr[4][64];
  const int wave = threadIdx.x >> 6, lane = threadIdx.x & 63;
  const int i = blockIdx.x * 4 + wave;  // grid exact: i < N1C
  int n = keep[i];
  int j0 = rp[n], j1 = rp[n + 1];
  float m = -INFINITY;
  for (int j = j0; j < j1; ++j) {
    int e = eidx[j];
    int src = (e < E0C) ? ei[e] : (e - E0C);
    m = fmaxf(m, hc0[(size_t)src * HC + lane]);
  }
  xr[wave][lane] = m;
  __syncthreads();
  const float px = ppos[i * 3], py = ppos[i * 3 + 1], pz = ppos[i * 3 + 2];
  float tl = 0.f, ds = 0.f;
#pragma unroll 8
  for (int f = 0; f < HC; ++f) {
    float xv = xr[wave][f];
    tl = fmaf(xv, w2t[f * HC + lane], tl);
    ds = fmaf(xv, b2[f], ds);
  }
  tl = fmaf(px, w2t[64 * HC + lane], fmaf(py, w2t[65 * HC + lane], fmaf(pz, w2t[66 * HC + lane], tl)));
  ds = fmaf(px, b2[64], fmaf(py, b2[65], fmaf(pz, b2[66], ds)));
  tN[i * HC + lane] = tl;
  if (lane == 0) dN[i] = ds;
}

// ---- reduce level-1 + final linear + sin ------------------------------------
__global__ void k_reduce1f(const float* __restrict__ msg, const int* __restrict__ eidx,
                           const int* __restrict__ rp, const float* __restrict__ bias,
                           const float* __restrict__ l1w, const float* __restrict__ l1b,
                           float* __restrict__ outp) {
  __shared__ float hr[4][64];
  const int wave = threadIdx.x >> 6, lane = threadIdx.x & 63;
  const int node = blockIdx.x * 4 + wave;  // grid exact: node < N1C
  int j0 = rp[node], j1 = rp[node + 1];
  float s = 0.f;
  for (int j = j0; j < j1; ++j) s += msg[(size_t)eidx[j] * HC + lane];
  hr[wave][lane] = sinf(0.01f * (s + bias[lane]));
  __syncthreads();
  if (lane < 32) {
    float o = l1b[lane];
#pragma unroll 8
    for (int c = 0; c < HC; ++c) o = fmaf(hr[wave][c], l1w[c * LATC + lane], o);
    outp[node * LATC + lane] = sinf(0.01f * o);
  }
}

extern "C" void kernel_launch(void* const* d_in, const int* in_sizes, int n_in,
                              void* d_out, int out_size, void* d_ws, size_t ws_size,
                              hipStream_t stream) {
  (void)in_sizes; (void)n_in; (void)out_size; (void)ws_size;
  const float* x    = (const float*)d_in[0];
  const float* pos  = (const float*)d_in[1];
  const int*   ei   = (const int*)d_in[2];
  const int*   pei  = (const int*)d_in[3];
  const float* ppos = (const float*)d_in[4];
  const int*   keep = (const int*)d_in[5];
  const float* l0w  = (const float*)d_in[6];
  const float* l0b  = (const float*)d_in[7];
  const float* l1w  = (const float*)d_in[8];
  const float* l1b  = (const float*)d_in[9];
  const float* c0w0 = (const float*)d_in[10];
  const float* c0b0 = (const float*)d_in[11];
  const float* c0w1 = (const float*)d_in[12];
  const float* c0b1 = (const float*)d_in[13];
  const float* c0w2 = (const float*)d_in[14];
  const float* c0b2 = (const float*)d_in[15];
  const float* c0bias = (const float*)d_in[16];
  const float* c1w0 = (const float*)d_in[17];
  const float* c1b0 = (const float*)d_in[18];
  const float* c1w1 = (const float*)d_in[19];
  const float* c1b1 = (const float*)d_in[20];
  const float* c1w2 = (const float*)d_in[21];
  const float* c1b2 = (const float*)d_in[22];
  const float* c1bias = (const float*)d_in[23];
  float* outp = (float*)d_out;

  char* p = (char*)d_ws;
  auto carve = [&](size_t bytes) -> char* {
    char* r = p;
    p += (bytes + 255) & ~(size_t)255;
    return r;
  };
  float* hc0  = (float*)carve((size_t)N0C * HC * 4);
  float* tN0  = (float*)carve((size_t)N0C * HC * 4);
  float* dN0  = (float*)carve((size_t)N0C * 4);
  float* tN1  = (float*)carve((size_t)N1C * HC * 4);
  float* dN1  = (float*)carve((size_t)N1C * 4);
  _Float16* bC0  = (_Float16*)carve(4096 * 2);
  _Float16* bS0  = (_Float16*)carve(4096 * 2);
  _Float16* bC1  = (_Float16*)carve(4096 * 2);
  _Float16* bS1  = (_Float16*)carve(4096 * 2);
  _Float16* w1f0 = (_Float16*)carve(4096 * 2);
  _Float16* w1f1 = (_Float16*)carve(4096 * 2);
  float* w2t0 = (float*)carve((size_t)FC * HC * 4);
  float* w2t1 = (float*)carve((size_t)FC * HC * 4);
  int* cnt  = (int*)carve((size_t)(N0C + N1C) * 4);
  int* fill = (int*)carve((size_t)(N0C + N1C) * 4);
  int* rp0 = (int*)carve((size_t)(N0C + 1) * 4);
  int* rp1 = (int*)carve((size_t)(N1C + 1) * 4);
  int* eidx0 = (int*)carve((size_t)E0T * 4);
  int* eidx1 = (int*)carve((size_t)E1T * 4);
  float* msg = (float*)carve((size_t)E0T * HC * 4);  // reused for level 1

  hipMemsetAsync(cnt, 0, (size_t)(N0C + N1C) * 4 * 2, stream);  // cnt + fill

  k_misc<<<214, 256, 0, stream>>>(c0w0, c1w0, c0w1, c1w1, c0w2, c1w2, ei, pei,
                                  bC0, bS0, bC1, bS1, w1f0, w1f1, w2t0, w2t1, cnt);
  k_scan<<<2, 1024, 0, stream>>>(cnt, rp0, rp1);
  k_scatter<<<(E0T + E1T + 255) / 256, 256, 0, stream>>>(ei, pei, rp0, rp1, fill,
                                                         eidx0, eidx1);
  k_node0<<<N0C / 4, 256, 0, stream>>>(x, l0w, l0b, pos, w2t0, c0b2, tN0, dN0);

  k_conv<<<512, 256, 0, stream>>>(ei, E0C, E0T, pos, tN0, dN0, c0w0, c0b0,
                                  bC0, bS0, w1f0, c0b1, msg);
  k_reduce<<<N0C / 4, 256, 0, stream>>>(msg, eidx0, rp0, c0bias, hc0, N0C);
  k_pool1<<<N1C / 4, 256, 0, stream>>>(hc0, eidx0, rp0, ei, keep, ppos, w2t1, c1b2,
                                       tN1, dN1);

  k_conv<<<512, 256, 0, stream>>>(pei, E1C, E1T, ppos, tN1, dN1, c1w0, c1b0,
                                  bC1, bS1, w1f1, c1b1, msg);
  k_reduce1f<<<N1C / 4, 256, 0, stream>>>(msg, eidx1, rp1, c1bias, l1w, l1b, outp);
}